// Round 2
// baseline (870.813 us; speedup 1.0000x reference)
//
#include <hip/hip_runtime.h>
#include <hip/hip_bf16.h>

#define NN 20000
#define EE 320000
#define LGN 4

typedef unsigned short u16;
typedef short bf16x8 __attribute__((ext_vector_type(8)));
typedef float f32x4 __attribute__((ext_vector_type(4)));

__device__ __forceinline__ float bf2f(u16 v) {
    unsigned int u = ((unsigned int)v) << 16;
    float f; __builtin_memcpy(&f, &u, 4); return f;
}
__device__ __forceinline__ u16 f2bf(float f) {
    __hip_bfloat16 h = __float2bfloat16(f);
    u16 u; __builtin_memcpy(&u, &h, 2); return u;
}

// ---- pass 1: degree (by source), col histogram, ew copy-out ----
__global__ __launch_bounds__(256) void k_edge1(const int* __restrict__ ei,
                                               const float* __restrict__ ew,
                                               float* __restrict__ deg,
                                               int* __restrict__ counts,
                                               float* __restrict__ out_ew) {
    int e = blockIdx.x * 256 + threadIdx.x;
    if (e >= EE) return;
    int r = ei[e];
    float w = ew[e];
    atomicAdd(&deg[r], w);
    atomicAdd(&counts[ei[EE + e]], 1);
    out_ew[e] = w;
}

__global__ __launch_bounds__(256) void k_rsqrt(float* __restrict__ deg) {
    int i = blockIdx.x * 256 + threadIdx.x;
    if (i >= NN) return;
    float d = deg[i];
    deg[i] = (d > 0.f) ? rsqrtf(d) : 0.f;
}

// ---- exclusive scan of col histogram (single block) ----
__global__ __launch_bounds__(1024) void k_scan(const int* __restrict__ counts,
                                               int* __restrict__ offs) {
    __shared__ int part[1024];
    int t = threadIdx.x;
    const int C = (NN + 1023) / 1024;  // 20
    int lo = t * C, hi = min(lo + C, NN);
    int s = 0;
    for (int i = lo; i < hi; i++) s += counts[i];
    part[t] = s;
    __syncthreads();
    for (int off = 1; off < 1024; off <<= 1) {
        int add = (t >= off) ? part[t - off] : 0;
        __syncthreads();
        part[t] += add;
        __syncthreads();
    }
    int base = part[t] - s;
    for (int i = lo; i < hi; i++) { offs[i] = base; base += counts[i]; }
    if (t == 1023) offs[NN] = part[1023];
}

// ---- pass 2: compute norm, scatter into CSR slots ----
__global__ __launch_bounds__(256) void k_scatter(const int* __restrict__ ei,
                                                 const float* __restrict__ ew,
                                                 const float* __restrict__ dis,
                                                 const int* __restrict__ offs,
                                                 int* __restrict__ cursor,
                                                 int* __restrict__ srow,
                                                 float* __restrict__ snorm) {
    int e = blockIdx.x * 256 + threadIdx.x;
    if (e >= EE) return;
    int r = ei[e], c = ei[EE + e];
    float nm = -(dis[r] * ew[e] * dis[c]);
    int pidx = offs[c] + atomicAdd(&cursor[c], 1);
    srow[pidx] = r;
    snorm[pidx] = nm;
}

// ---- f32 -> bf16 cast (no transpose) ----
__global__ __launch_bounds__(256) void k_cast(const float* __restrict__ src,
                                              u16* __restrict__ dst, int n) {
    int i = blockIdx.x * 256 + threadIdx.x;
    if (i < n) dst[i] = f2bf(src[i]);
}

// ---- f32 [K][256] -> bf16 [256][K] transpose-cast (weights) ----
__global__ __launch_bounds__(256) void k_cast_T(const float* __restrict__ src,
                                                u16* __restrict__ dst, int K) {
    __shared__ u16 tile[32][33];
    int kt = blockIdx.x * 32, nt = blockIdx.y * 32;
    int tx = threadIdx.x & 31, ty = threadIdx.x >> 5;  // 32 x 8
#pragma unroll
    for (int i = 0; i < 32; i += 8)
        tile[ty + i][tx] = f2bf(src[(size_t)(kt + ty + i) * 256 + (nt + tx)]);
    __syncthreads();
#pragma unroll
    for (int i = 0; i < 32; i += 8)
        dst[(size_t)(nt + ty + i) * K + (kt + tx)] = tile[tx][ty + i];
}

// ---- fold BN affine: s = gamma*rsqrt(var+eps), t = beta - mean*s ----
__global__ __launch_bounds__(256) void k_foldbn(const float* __restrict__ g,
                                                const float* __restrict__ be,
                                                const float* __restrict__ mn,
                                                const float* __restrict__ vr,
                                                float* __restrict__ sc,
                                                float* __restrict__ sh) {
    int t = threadIdx.x;
    if (t < 256) {
        float s = g[t] * rsqrtf(vr[t] + 1e-5f);
        sc[t] = s;
        sh[t] = be[t] - mn[t] * s;
    }
}

// ---- CSR SpMM: out[c,:] = (dotx2 ? 2*S.x - xsub : S.x), bf16 in/out ----
__global__ __launch_bounds__(256) void k_prop(const u16* __restrict__ x, int ldx,
                                              const u16* __restrict__ xsub, int ldsub,
                                              int dotx2,
                                              u16* __restrict__ out, int ldo,
                                              const int* __restrict__ offs,
                                              const int* __restrict__ srow,
                                              const float* __restrict__ snorm) {
    int c = blockIdx.x, d = threadIdx.x;
    __shared__ int rb[256];
    __shared__ float wb[256];
    int s = offs[c], e = offs[c + 1];
    float acc = 0.f;
    for (int base = s; base < e; base += 256) {
        int cnt = min(256, e - base);
        if (d < cnt) { rb[d] = srow[base + d]; wb[d] = snorm[base + d]; }
        __syncthreads();
        for (int i = 0; i < cnt; i++)
            acc += wb[i] * bf2f(x[(size_t)rb[i] * ldx + d]);
        __syncthreads();
    }
    float r = acc;
    if (dotx2) r = 2.f * acc - bf2f(xsub[(size_t)c * ldsub + d]);
    out[(size_t)c * ldo + d] = f2bf(r);
}

// ---- bf16 MFMA GEMM: C[m,0:256] = A[m,:] @ Bt[n,:]^T ----
// Block: 256 threads / 4 waves; tile M=64 x N=256 (wave w owns n = w*64..w*64+63).
// Bt is [256][K] row-major (pre-transposed weights) so both A and B stage as
// k-contiguous rows -> all LDS traffic is b128 with stride-40 padding
// (80 B = 5 x 16 B chunks -> 2-way aliasing, free).
// mode 0: relu -> bf16 outb (stride ldob)
// mode 1: +bias, relu, *sc + sh -> f32 outf (stride 256)
__global__ __launch_bounds__(256) void k_gemm(
    const u16* __restrict__ A0, const u16* __restrict__ A1,
    const u16* __restrict__ A2, const u16* __restrict__ A3,
    int lda0, int lda1, int lda2, int lda3,
    int K, const u16* __restrict__ Bt,
    int mode,
    u16* __restrict__ outb, int ldob,
    float* __restrict__ outf,
    const float* __restrict__ bias, const float* __restrict__ sc,
    const float* __restrict__ sh) {
    const u16* Ap[4] = {A0, A1, A2, A3};
    int lda[4] = {lda0, lda1, lda2, lda3};
    __shared__ __align__(16) short As[64][40];
    __shared__ __align__(16) short Bs[256][40];
    int t = threadIdx.x;
    int m0 = blockIdx.x * 64;
    int wv = t >> 6, lane = t & 63, quad = lane >> 4, l16 = lane & 15;
    f32x4 acc[4][4] = {};
    int arow = t >> 2, akoff = (t & 3) * 8;

    for (int kt = 0; kt < K; kt += 32) {
        // issue global loads for this k-tile
        uint4 av = make_uint4(0u, 0u, 0u, 0u);
        int m = m0 + arow;
        if (m < NN) {
            int kg = kt + akoff;
            int ch = kg >> 8;
            av = *(const uint4*)(Ap[ch] + (size_t)m * lda[ch] + (kg & 255));
        }
        uint4 bv[4];
        const u16* bp = Bt + (size_t)t * K + kt;
#pragma unroll
        for (int j = 0; j < 4; j++) bv[j] = *(const uint4*)(bp + j * 8);
        __syncthreads();  // prev iter done reading LDS
        *(uint4*)&As[arow][akoff] = av;
#pragma unroll
        for (int j = 0; j < 4; j++) *(uint4*)&Bs[t][j * 8] = bv[j];
        __syncthreads();

        bf16x8 a[4];
#pragma unroll
        for (int mt = 0; mt < 4; mt++)
            a[mt] = *(const bf16x8*)&As[mt * 16 + l16][quad * 8];
#pragma unroll
        for (int nt = 0; nt < 4; nt++) {
            bf16x8 b = *(const bf16x8*)&Bs[wv * 64 + nt * 16 + l16][quad * 8];
#pragma unroll
            for (int mt = 0; mt < 4; mt++)
                acc[mt][nt] =
                    __builtin_amdgcn_mfma_f32_16x16x32_bf16(a[mt], b, acc[mt][nt], 0, 0, 0);
        }
    }

#pragma unroll
    for (int nt = 0; nt < 4; nt++) {
        int col = wv * 64 + nt * 16 + l16;
#pragma unroll
        for (int mt = 0; mt < 4; mt++) {
#pragma unroll
            for (int i = 0; i < 4; i++) {
                int row = m0 + mt * 16 + quad * 4 + i;
                if (row >= NN) continue;
                float v = acc[mt][nt][i];
                if (mode == 0) {
                    v = v > 0.f ? v : 0.f;
                    outb[(size_t)row * ldob + col] = f2bf(v);
                } else {
                    v += bias[col];
                    v = v > 0.f ? v : 0.f;
                    v = v * sc[col] + sh[col];
                    outf[(size_t)row * 256 + col] = v;
                }
            }
        }
    }
}

// ---- final projection: logit[n,k] = z[n,:] @ w2[:,k] + b2[k], one wave/node ----
__global__ __launch_bounds__(256) void k_final(const float* __restrict__ z,
                                               const float* __restrict__ w2,
                                               const float* __restrict__ b2,
                                               float* __restrict__ out) {
    int wave = threadIdx.x >> 6, lane = threadIdx.x & 63;
    int n = blockIdx.x * 4 + wave;
    if (n >= NN) return;
    const float* zr = z + (size_t)n * 256;
    int j = lane * 4;
    float4 zv = *(const float4*)(zr + j);
    float4 wa = *(const float4*)(w2 + j * 2);
    float4 wb = *(const float4*)(w2 + j * 2 + 4);
    float a0 = zv.x * wa.x + zv.y * wa.z + zv.z * wb.x + zv.w * wb.z;
    float a1 = zv.x * wa.y + zv.y * wa.w + zv.z * wb.y + zv.w * wb.w;
    for (int off = 32; off; off >>= 1) {
        a0 += __shfl_down(a0, off, 64);
        a1 += __shfl_down(a1, off, 64);
    }
    if (lane == 0) {
        out[n * 2 + 0] = a0 + b2[0];
        out[n * 2 + 1] = a1 + b2[1];
    }
}

extern "C" void kernel_launch(void* const* d_in, const int* in_sizes, int n_in,
                              void* d_out, int out_size, void* d_ws, size_t ws_size,
                              hipStream_t stream) {
    const float* features = (const float*)d_in[0];
    const int* ei = (const int*)d_in[1];
    // d_in[2] = edgenet_input (bypassed by edge_weight_override)
    const float* ew = (const float*)d_in[3];
    const float* cheb_w = (const float*)d_in[4];
    const float* w1 = (const float*)d_in[5];
    const float* b1 = (const float*)d_in[6];
    const float* g = (const float*)d_in[7];
    const float* be = (const float*)d_in[8];
    const float* mn = (const float*)d_in[9];
    const float* vr = (const float*)d_in[10];
    const float* w2 = (const float*)d_in[11];
    const float* b2 = (const float*)d_in[12];
    float* out = (float*)d_out;  // [NN*2] logits, then [EE] ew

    char* p = (char*)d_ws;
    auto alloc = [&](size_t bytes) -> char* {
        char* r = p;
        p += (bytes + 255) & ~(size_t)255;
        return r;
    };
    float* deg = (float*)alloc((size_t)NN * 4);
    int* counts = (int*)alloc((size_t)(NN + 1) * 4);
    int* cursor = (int*)alloc((size_t)NN * 4);
    size_t zero_bytes = (size_t)(p - (char*)deg);
    int* offs = (int*)alloc((size_t)(NN + 1) * 4);
    int* srow = (int*)alloc((size_t)EE * 4);
    float* snorm = (float*)alloc((size_t)EE * 4);
    u16* xb = (u16*)alloc((size_t)NN * 256 * 2);
    u16* tx1 = (u16*)alloc((size_t)NN * 256 * 2);
    u16* tx2 = (u16*)alloc((size_t)NN * 256 * 2);
    float* z = (float*)tx1;  // overlay: z (N*256 f32) reuses tx1+tx2 (contiguous)
    u16* jk = (u16*)alloc((size_t)NN * 1024 * 2);
    u16* chebT = (u16*)alloc((size_t)LGN * 3 * 256 * 256 * 2);  // per layer [256][768]
    u16* w1T = (u16*)alloc((size_t)1024 * 256 * 2);             // [256][1024]
    float* sc = (float*)alloc(256 * 4);
    float* sh = (float*)alloc(256 * 4);

    hipMemsetAsync(deg, 0, zero_bytes, stream);
    k_edge1<<<(EE + 255) / 256, 256, 0, stream>>>(ei, ew, deg, counts, out + (size_t)NN * 2);
    k_rsqrt<<<(NN + 255) / 256, 256, 0, stream>>>(deg);
    k_scan<<<1, 1024, 0, stream>>>(counts, offs);
    k_scatter<<<(EE + 255) / 256, 256, 0, stream>>>(ei, ew, deg, offs, cursor, srow, snorm);
    k_cast<<<((NN * 256) + 255) / 256, 256, 0, stream>>>(features, xb, NN * 256);
    for (int i = 0; i < LGN; i++)
        k_cast_T<<<dim3(24, 8), 256, 0, stream>>>(cheb_w + (size_t)i * 768 * 256,
                                                  chebT + (size_t)i * 256 * 768, 768);
    k_cast_T<<<dim3(32, 8), 256, 0, stream>>>(w1, w1T, 1024);
    k_foldbn<<<1, 256, 0, stream>>>(g, be, mn, vr, sc, sh);

    for (int i = 0; i < LGN; i++) {
        const u16* x = (i == 0) ? xb : (jk + (size_t)(i - 1) * 256);
        int ldx = (i == 0) ? 256 : 1024;
        k_prop<<<NN, 256, 0, stream>>>(x, ldx, (const u16*)nullptr, 0, 0, tx1, 256, offs, srow,
                                       snorm);
        k_prop<<<NN, 256, 0, stream>>>(tx1, 256, x, ldx, 1, tx2, 256, offs, srow, snorm);
        k_gemm<<<313, 256, 0, stream>>>(
            x, tx1, tx2, (const u16*)nullptr, ldx, 256, 256, 0, 768,
            chebT + (size_t)i * 256 * 768, 0, jk + (size_t)i * 256, 1024, (float*)nullptr,
            (const float*)nullptr, (const float*)nullptr, (const float*)nullptr);
    }
    k_gemm<<<313, 256, 0, stream>>>(jk, jk + 256, jk + 512, jk + 768, 1024, 1024, 1024, 1024,
                                    1024, w1T, 1, (u16*)nullptr, 0, z, b1, sc, sh);
    k_final<<<5000, 256, 0, stream>>>(z, w2, b2, out);
}

// Round 3
// 788.213 us; speedup vs baseline: 1.1048x; 1.1048x over previous
//
#include <hip/hip_runtime.h>
#include <hip/hip_bf16.h>

#define NN 20000
#define EE 320000
#define LGN 4

typedef unsigned short u16;
typedef short bf16x8 __attribute__((ext_vector_type(8)));
typedef float f32x4 __attribute__((ext_vector_type(4)));

__device__ __forceinline__ float bf2f(u16 v) {
    unsigned int u = ((unsigned int)v) << 16;
    float f; __builtin_memcpy(&f, &u, 4); return f;
}
__device__ __forceinline__ u16 f2bf(float f) {
    __hip_bfloat16 h = __float2bfloat16(f);
    u16 u; __builtin_memcpy(&u, &h, 2); return u;
}

// ---- pass 1: degree (by source), col histogram, ew copy-out ----
__global__ __launch_bounds__(256) void k_edge1(const int* __restrict__ ei,
                                               const float* __restrict__ ew,
                                               float* __restrict__ deg,
                                               int* __restrict__ counts,
                                               float* __restrict__ out_ew) {
    int e = blockIdx.x * 256 + threadIdx.x;
    if (e >= EE) return;
    int r = ei[e];
    float w = ew[e];
    atomicAdd(&deg[r], w);
    atomicAdd(&counts[ei[EE + e]], 1);
    out_ew[e] = w;
}

__global__ __launch_bounds__(256) void k_rsqrt(float* __restrict__ deg) {
    int i = blockIdx.x * 256 + threadIdx.x;
    if (i >= NN) return;
    float d = deg[i];
    deg[i] = (d > 0.f) ? rsqrtf(d) : 0.f;
}

// ---- exclusive scan of col histogram (single block) ----
__global__ __launch_bounds__(1024) void k_scan(const int* __restrict__ counts,
                                               int* __restrict__ offs) {
    __shared__ int part[1024];
    int t = threadIdx.x;
    const int C = (NN + 1023) / 1024;  // 20
    int lo = t * C, hi = min(lo + C, NN);
    int s = 0;
    for (int i = lo; i < hi; i++) s += counts[i];
    part[t] = s;
    __syncthreads();
    for (int off = 1; off < 1024; off <<= 1) {
        int add = (t >= off) ? part[t - off] : 0;
        __syncthreads();
        part[t] += add;
        __syncthreads();
    }
    int base = part[t] - s;
    for (int i = lo; i < hi; i++) { offs[i] = base; base += counts[i]; }
    if (t == 1023) offs[NN] = part[1023];
}

// ---- pass 2: compute norm, scatter into CSR slots ----
__global__ __launch_bounds__(256) void k_scatter(const int* __restrict__ ei,
                                                 const float* __restrict__ ew,
                                                 const float* __restrict__ dis,
                                                 const int* __restrict__ offs,
                                                 int* __restrict__ cursor,
                                                 int* __restrict__ srow,
                                                 float* __restrict__ snorm) {
    int e = blockIdx.x * 256 + threadIdx.x;
    if (e >= EE) return;
    int r = ei[e], c = ei[EE + e];
    float nm = -(dis[r] * ew[e] * dis[c]);
    int pidx = offs[c] + atomicAdd(&cursor[c], 1);
    srow[pidx] = r;
    snorm[pidx] = nm;
}

// ---- f32 -> bf16 cast (no transpose) ----
__global__ __launch_bounds__(256) void k_cast(const float* __restrict__ src,
                                              u16* __restrict__ dst, int n) {
    int i = blockIdx.x * 256 + threadIdx.x;
    if (i < n) dst[i] = f2bf(src[i]);
}

// ---- f32 [K][256] -> bf16 [256][K] transpose-cast (weights) ----
__global__ __launch_bounds__(256) void k_cast_T(const float* __restrict__ src,
                                                u16* __restrict__ dst, int K) {
    __shared__ u16 tile[32][33];
    int kt = blockIdx.x * 32, nt = blockIdx.y * 32;
    int tx = threadIdx.x & 31, ty = threadIdx.x >> 5;  // 32 x 8
#pragma unroll
    for (int i = 0; i < 32; i += 8)
        tile[ty + i][tx] = f2bf(src[(size_t)(kt + ty + i) * 256 + (nt + tx)]);
    __syncthreads();
#pragma unroll
    for (int i = 0; i < 32; i += 8)
        dst[(size_t)(nt + ty + i) * K + (kt + tx)] = tile[tx][ty + i];
}

// ---- fold BN affine: s = gamma*rsqrt(var+eps), t = beta - mean*s ----
__global__ __launch_bounds__(256) void k_foldbn(const float* __restrict__ g,
                                                const float* __restrict__ be,
                                                const float* __restrict__ mn,
                                                const float* __restrict__ vr,
                                                float* __restrict__ sc,
                                                float* __restrict__ sh) {
    int t = threadIdx.x;
    if (t < 256) {
        float s = g[t] * rsqrtf(vr[t] + 1e-5f);
        sc[t] = s;
        sh[t] = be[t] - mn[t] * s;
    }
}

// ---- CSR SpMM: out[c,:] = (dotx2 ? 2*S.x - xsub : S.x), bf16 in/out ----
// 4 neighbors in flight (one per wave), ushort4 loads (8 B/lane, 64 lanes = 256 dims),
// cross-wave LDS reduction at the end.
__global__ __launch_bounds__(256) void k_prop(const u16* __restrict__ x, int ldx,
                                              const u16* __restrict__ xsub, int ldsub,
                                              int dotx2,
                                              u16* __restrict__ out, int ldo,
                                              const int* __restrict__ offs,
                                              const int* __restrict__ srow,
                                              const float* __restrict__ snorm) {
    int c = blockIdx.x;
    int t = threadIdx.x, wv = t >> 6, lane = t & 63;
    __shared__ int rb[64];
    __shared__ float wb[64];
    __shared__ float red[4][256];
    int s = offs[c], e = offs[c + 1];
    float ax = 0.f, ay = 0.f, az = 0.f, aw = 0.f;
    for (int base = s; base < e; base += 64) {
        int cnt = min(64, e - base);
        if (t < cnt) { rb[t] = srow[base + t]; wb[t] = snorm[base + t]; }
        __syncthreads();
        for (int i = wv; i < cnt; i += 4) {
            float w = wb[i];
            ushort4 xv = *(const ushort4*)(x + (size_t)rb[i] * ldx + lane * 4);
            ax += w * bf2f(xv.x);
            ay += w * bf2f(xv.y);
            az += w * bf2f(xv.z);
            aw += w * bf2f(xv.w);
        }
        __syncthreads();
    }
    red[wv][lane * 4 + 0] = ax;
    red[wv][lane * 4 + 1] = ay;
    red[wv][lane * 4 + 2] = az;
    red[wv][lane * 4 + 3] = aw;
    __syncthreads();
    if (wv == 0) {
        float r[4];
#pragma unroll
        for (int j = 0; j < 4; j++)
            r[j] = red[0][lane * 4 + j] + red[1][lane * 4 + j] + red[2][lane * 4 + j] +
                   red[3][lane * 4 + j];
        if (dotx2) {
            ushort4 xs = *(const ushort4*)(xsub + (size_t)c * ldsub + lane * 4);
            r[0] = 2.f * r[0] - bf2f(xs.x);
            r[1] = 2.f * r[1] - bf2f(xs.y);
            r[2] = 2.f * r[2] - bf2f(xs.z);
            r[3] = 2.f * r[3] - bf2f(xs.w);
        }
        ushort4 o;
        o.x = f2bf(r[0]); o.y = f2bf(r[1]); o.z = f2bf(r[2]); o.w = f2bf(r[3]);
        *(ushort4*)(out + (size_t)c * ldo + lane * 4) = o;
    }
}

// ---- bf16 MFMA GEMM: C[m,0:256] = A[m,:] @ Bt[n,:]^T ----
// Block: 256 threads / 4 waves; tile M=64 x N=256 (wave w owns n = w*64..w*64+63).
// Bt [256][K] row-major. Coalesced staging (4 lanes per row) + register prefetch
// pipeline: global loads for tile k+1 issue before computing tile k.
// mode 0: relu -> bf16 outb (stride ldob)
// mode 1: +bias, relu, *sc + sh -> f32 outf (stride 256)
__global__ __launch_bounds__(256) void k_gemm(
    const u16* __restrict__ A0, const u16* __restrict__ A1,
    const u16* __restrict__ A2, const u16* __restrict__ A3,
    int lda0, int lda1, int lda2, int lda3,
    int K, const u16* __restrict__ Bt,
    int mode,
    u16* __restrict__ outb, int ldob,
    float* __restrict__ outf,
    const float* __restrict__ bias, const float* __restrict__ sc,
    const float* __restrict__ sh) {
    const u16* Ap[4] = {A0, A1, A2, A3};
    int lda[4] = {lda0, lda1, lda2, lda3};
    __shared__ __align__(16) short As[64][40];
    __shared__ __align__(16) short Bs[256][40];
    int t = threadIdx.x;
    int m0 = blockIdx.x * 64;
    int wv = t >> 6, lane = t & 63, quad = lane >> 4, l16 = lane & 15;
    f32x4 acc[4][4] = {};
    int arow = t >> 2, koff = (t & 3) * 8;  // 4 lanes per row, 64-B row segments

    uint4 av;
    uint4 bv[4];
    {
        av = make_uint4(0u, 0u, 0u, 0u);
        int m = m0 + arow;
        if (m < NN) av = *(const uint4*)(Ap[0] + (size_t)m * lda[0] + koff);
#pragma unroll
        for (int j = 0; j < 4; j++)
            bv[j] = *(const uint4*)(Bt + (size_t)(arow + 64 * j) * K + koff);
    }

    for (int kt = 0; kt < K; kt += 32) {
        __syncthreads();  // prev compute done reading LDS
        *(uint4*)&As[arow][koff] = av;
#pragma unroll
        for (int j = 0; j < 4; j++) *(uint4*)&Bs[arow + 64 * j][koff] = bv[j];
        __syncthreads();
        int kn = kt + 32;
        if (kn < K) {  // prefetch next k-tile; overlaps with compute below
            av = make_uint4(0u, 0u, 0u, 0u);
            int m = m0 + arow;
            if (m < NN) {
                int kg = kn + koff;
                int ch = kg >> 8;
                av = *(const uint4*)(Ap[ch] + (size_t)m * lda[ch] + (kg & 255));
            }
#pragma unroll
            for (int j = 0; j < 4; j++)
                bv[j] = *(const uint4*)(Bt + (size_t)(arow + 64 * j) * K + kn + koff);
        }
        bf16x8 a[4], b[4];
#pragma unroll
        for (int mt = 0; mt < 4; mt++) a[mt] = *(const bf16x8*)&As[mt * 16 + l16][quad * 8];
#pragma unroll
        for (int nt = 0; nt < 4; nt++)
            b[nt] = *(const bf16x8*)&Bs[wv * 64 + nt * 16 + l16][quad * 8];
#pragma unroll
        for (int nt = 0; nt < 4; nt++)
#pragma unroll
            for (int mt = 0; mt < 4; mt++)
                acc[mt][nt] =
                    __builtin_amdgcn_mfma_f32_16x16x32_bf16(a[mt], b[nt], acc[mt][nt], 0, 0, 0);
    }

#pragma unroll
    for (int nt = 0; nt < 4; nt++) {
        int col = wv * 64 + nt * 16 + l16;
#pragma unroll
        for (int mt = 0; mt < 4; mt++) {
#pragma unroll
            for (int i = 0; i < 4; i++) {
                int row = m0 + mt * 16 + quad * 4 + i;
                if (row >= NN) continue;
                float v = acc[mt][nt][i];
                if (mode == 0) {
                    v = v > 0.f ? v : 0.f;
                    outb[(size_t)row * ldob + col] = f2bf(v);
                } else {
                    v += bias[col];
                    v = v > 0.f ? v : 0.f;
                    v = v * sc[col] + sh[col];
                    outf[(size_t)row * 256 + col] = v;
                }
            }
        }
    }
}

// ---- final projection: logit[n,k] = z[n,:] @ w2[:,k] + b2[k], one wave/node ----
__global__ __launch_bounds__(256) void k_final(const float* __restrict__ z,
                                               const float* __restrict__ w2,
                                               const float* __restrict__ b2,
                                               float* __restrict__ out) {
    int wave = threadIdx.x >> 6, lane = threadIdx.x & 63;
    int n = blockIdx.x * 4 + wave;
    if (n >= NN) return;
    const float* zr = z + (size_t)n * 256;
    int j = lane * 4;
    float4 zv = *(const float4*)(zr + j);
    float4 wa = *(const float4*)(w2 + j * 2);
    float4 wb = *(const float4*)(w2 + j * 2 + 4);
    float a0 = zv.x * wa.x + zv.y * wa.z + zv.z * wb.x + zv.w * wb.z;
    float a1 = zv.x * wa.y + zv.y * wa.w + zv.z * wb.y + zv.w * wb.w;
    for (int off = 32; off; off >>= 1) {
        a0 += __shfl_down(a0, off, 64);
        a1 += __shfl_down(a1, off, 64);
    }
    if (lane == 0) {
        out[n * 2 + 0] = a0 + b2[0];
        out[n * 2 + 1] = a1 + b2[1];
    }
}

extern "C" void kernel_launch(void* const* d_in, const int* in_sizes, int n_in,
                              void* d_out, int out_size, void* d_ws, size_t ws_size,
                              hipStream_t stream) {
    const float* features = (const float*)d_in[0];
    const int* ei = (const int*)d_in[1];
    // d_in[2] = edgenet_input (bypassed by edge_weight_override)
    const float* ew = (const float*)d_in[3];
    const float* cheb_w = (const float*)d_in[4];
    const float* w1 = (const float*)d_in[5];
    const float* b1 = (const float*)d_in[6];
    const float* g = (const float*)d_in[7];
    const float* be = (const float*)d_in[8];
    const float* mn = (const float*)d_in[9];
    const float* vr = (const float*)d_in[10];
    const float* w2 = (const float*)d_in[11];
    const float* b2 = (const float*)d_in[12];
    float* out = (float*)d_out;  // [NN*2] logits, then [EE] ew

    char* p = (char*)d_ws;
    auto alloc = [&](size_t bytes) -> char* {
        char* r = p;
        p += (bytes + 255) & ~(size_t)255;
        return r;
    };
    float* deg = (float*)alloc((size_t)NN * 4);
    int* counts = (int*)alloc((size_t)(NN + 1) * 4);
    int* cursor = (int*)alloc((size_t)NN * 4);
    size_t zero_bytes = (size_t)(p - (char*)deg);
    int* offs = (int*)alloc((size_t)(NN + 1) * 4);
    int* srow = (int*)alloc((size_t)EE * 4);
    float* snorm = (float*)alloc((size_t)EE * 4);
    u16* xb = (u16*)alloc((size_t)NN * 256 * 2);
    u16* tx1 = (u16*)alloc((size_t)NN * 256 * 2);
    u16* tx2 = (u16*)alloc((size_t)NN * 256 * 2);
    float* z = (float*)tx1;  // overlay: z (N*256 f32) reuses tx1+tx2 (contiguous)
    u16* jk = (u16*)alloc((size_t)NN * 1024 * 2);
    u16* chebT = (u16*)alloc((size_t)LGN * 3 * 256 * 256 * 2);  // per layer [256][768]
    u16* w1T = (u16*)alloc((size_t)1024 * 256 * 2);             // [256][1024]
    float* sc = (float*)alloc(256 * 4);
    float* sh = (float*)alloc(256 * 4);

    hipMemsetAsync(deg, 0, zero_bytes, stream);
    k_edge1<<<(EE + 255) / 256, 256, 0, stream>>>(ei, ew, deg, counts, out + (size_t)NN * 2);
    k_rsqrt<<<(NN + 255) / 256, 256, 0, stream>>>(deg);
    k_scan<<<1, 1024, 0, stream>>>(counts, offs);
    k_scatter<<<(EE + 255) / 256, 256, 0, stream>>>(ei, ew, deg, offs, cursor, srow, snorm);
    k_cast<<<((NN * 256) + 255) / 256, 256, 0, stream>>>(features, xb, NN * 256);
    for (int i = 0; i < LGN; i++)
        k_cast_T<<<dim3(24, 8), 256, 0, stream>>>(cheb_w + (size_t)i * 768 * 256,
                                                  chebT + (size_t)i * 256 * 768, 768);
    k_cast_T<<<dim3(32, 8), 256, 0, stream>>>(w1, w1T, 1024);
    k_foldbn<<<1, 256, 0, stream>>>(g, be, mn, vr, sc, sh);

    for (int i = 0; i < LGN; i++) {
        const u16* x = (i == 0) ? xb : (jk + (size_t)(i - 1) * 256);
        int ldx = (i == 0) ? 256 : 1024;
        k_prop<<<NN, 256, 0, stream>>>(x, ldx, (const u16*)nullptr, 0, 0, tx1, 256, offs, srow,
                                       snorm);
        k_prop<<<NN, 256, 0, stream>>>(tx1, 256, x, ldx, 1, tx2, 256, offs, srow, snorm);
        k_gemm<<<313, 256, 0, stream>>>(
            x, tx1, tx2, (const u16*)nullptr, ldx, 256, 256, 0, 768,
            chebT + (size_t)i * 256 * 768, 0, jk + (size_t)i * 256, 1024, (float*)nullptr,
            (const float*)nullptr, (const float*)nullptr, (const float*)nullptr);
    }
    k_gemm<<<313, 256, 0, stream>>>(jk, jk + 256, jk + 512, jk + 768, 1024, 1024, 1024, 1024,
                                    1024, w1T, 1, (u16*)nullptr, 0, z, b1, sc, sh);
    k_final<<<5000, 256, 0, stream>>>(z, w2, b2, out);
}

// Round 4
// 654.318 us; speedup vs baseline: 1.3309x; 1.2046x over previous
//
#include <hip/hip_runtime.h>
#include <hip/hip_bf16.h>

#define NN 20000
#define EE 320000
#define LGN 4

typedef unsigned short u16;
typedef short bf16x8 __attribute__((ext_vector_type(8)));
typedef float f32x4 __attribute__((ext_vector_type(4)));

__device__ __forceinline__ float bf2f(u16 v) {
    unsigned int u = ((unsigned int)v) << 16;
    float f; __builtin_memcpy(&f, &u, 4); return f;
}
__device__ __forceinline__ u16 f2bf(float f) {
    __hip_bfloat16 h = __float2bfloat16(f);
    u16 u; __builtin_memcpy(&u, &h, 2); return u;
}

// ---- pass 1: degree (by source), col histogram, ew copy-out ----
__global__ __launch_bounds__(256) void k_edge1(const int* __restrict__ ei,
                                               const float* __restrict__ ew,
                                               float* __restrict__ deg,
                                               int* __restrict__ counts,
                                               float* __restrict__ out_ew) {
    int e = blockIdx.x * 256 + threadIdx.x;
    if (e >= EE) return;
    int r = ei[e];
    float w = ew[e];
    atomicAdd(&deg[r], w);
    atomicAdd(&counts[ei[EE + e]], 1);
    out_ew[e] = w;
}

__global__ __launch_bounds__(256) void k_rsqrt(float* __restrict__ deg) {
    int i = blockIdx.x * 256 + threadIdx.x;
    if (i >= NN) return;
    float d = deg[i];
    deg[i] = (d > 0.f) ? rsqrtf(d) : 0.f;
}

// ---- exclusive scan of col histogram (single block) ----
__global__ __launch_bounds__(1024) void k_scan(const int* __restrict__ counts,
                                               int* __restrict__ offs) {
    __shared__ int part[1024];
    int t = threadIdx.x;
    const int C = (NN + 1023) / 1024;  // 20
    int lo = t * C, hi = min(lo + C, NN);
    int s = 0;
    for (int i = lo; i < hi; i++) s += counts[i];
    part[t] = s;
    __syncthreads();
    for (int off = 1; off < 1024; off <<= 1) {
        int add = (t >= off) ? part[t - off] : 0;
        __syncthreads();
        part[t] += add;
        __syncthreads();
    }
    int base = part[t] - s;
    for (int i = lo; i < hi; i++) { offs[i] = base; base += counts[i]; }
    if (t == 1023) offs[NN] = part[1023];
}

// ---- pass 2: compute norm, scatter (row, norm) int2 into CSR slots ----
__global__ __launch_bounds__(256) void k_scatter(const int* __restrict__ ei,
                                                 const float* __restrict__ ew,
                                                 const float* __restrict__ dis,
                                                 const int* __restrict__ offs,
                                                 int* __restrict__ cursor,
                                                 int2* __restrict__ nbrs) {
    int e = blockIdx.x * 256 + threadIdx.x;
    if (e >= EE) return;
    int r = ei[e], c = ei[EE + e];
    float nm = -(dis[r] * ew[e] * dis[c]);
    int pidx = offs[c] + atomicAdd(&cursor[c], 1);
    nbrs[pidx] = make_int2(r, __float_as_int(nm));
}

// ---- f32 -> bf16 cast (no transpose) ----
__global__ __launch_bounds__(256) void k_cast(const float* __restrict__ src,
                                              u16* __restrict__ dst, int n) {
    int i = blockIdx.x * 256 + threadIdx.x;
    if (i < n) dst[i] = f2bf(src[i]);
}

// ---- f32 [K][256] -> bf16 [256][K] transpose-cast (weights) ----
__global__ __launch_bounds__(256) void k_cast_T(const float* __restrict__ src,
                                                u16* __restrict__ dst, int K) {
    __shared__ u16 tile[32][33];
    int kt = blockIdx.x * 32, nt = blockIdx.y * 32;
    int tx = threadIdx.x & 31, ty = threadIdx.x >> 5;  // 32 x 8
#pragma unroll
    for (int i = 0; i < 32; i += 8)
        tile[ty + i][tx] = f2bf(src[(size_t)(kt + ty + i) * 256 + (nt + tx)]);
    __syncthreads();
#pragma unroll
    for (int i = 0; i < 32; i += 8)
        dst[(size_t)(nt + ty + i) * K + (kt + tx)] = tile[tx][ty + i];
}

// ---- fold BN affine: s = gamma*rsqrt(var+eps), t = beta - mean*s ----
__global__ __launch_bounds__(256) void k_foldbn(const float* __restrict__ g,
                                                const float* __restrict__ be,
                                                const float* __restrict__ mn,
                                                const float* __restrict__ vr,
                                                float* __restrict__ sc,
                                                float* __restrict__ sh) {
    int t = threadIdx.x;
    if (t < 256) {
        float s = g[t] * rsqrtf(vr[t] + 1e-5f);
        sc[t] = s;
        sh[t] = be[t] - mn[t] * s;
    }
}

// ---- CSR SpMM: one WAVE per node, no LDS, no barriers. ----
// Wave-uniform CSR walk (readfirstlane -> scalar loads of packed int2 meta),
// 4 neighbor gathers in flight, 64 lanes x ushort4 = 256 dims.
__global__ __launch_bounds__(256) void k_prop(const u16* __restrict__ x, int ldx,
                                              const u16* __restrict__ xsub, int ldsub,
                                              int dotx2,
                                              u16* __restrict__ out, int ldo,
                                              const int* __restrict__ offs,
                                              const int2* __restrict__ nbrs) {
    int c = __builtin_amdgcn_readfirstlane(blockIdx.x * 4 + (threadIdx.x >> 6));
    int lane = threadIdx.x & 63;
    int s = offs[c], e = offs[c + 1];
    float a0 = 0.f, a1 = 0.f, a2 = 0.f, a3 = 0.f;
    for (int i = s; i < e; i += 4) {
        int2 m0 = nbrs[i];
        int2 m1 = nbrs[i + 1];
        int2 m2 = nbrs[i + 2];
        int2 m3 = nbrs[i + 3];
        ushort4 x0 = *(const ushort4*)(x + (size_t)m0.x * ldx + lane * 4);
        ushort4 x1 = *(const ushort4*)(x + (size_t)m1.x * ldx + lane * 4);
        ushort4 x2 = *(const ushort4*)(x + (size_t)m2.x * ldx + lane * 4);
        ushort4 x3 = *(const ushort4*)(x + (size_t)m3.x * ldx + lane * 4);
        float w0 = __int_as_float(m0.y);
        float w1 = (i + 1 < e) ? __int_as_float(m1.y) : 0.f;
        float w2 = (i + 2 < e) ? __int_as_float(m2.y) : 0.f;
        float w3 = (i + 3 < e) ? __int_as_float(m3.y) : 0.f;
        a0 += w0 * bf2f(x0.x) + w1 * bf2f(x1.x) + w2 * bf2f(x2.x) + w3 * bf2f(x3.x);
        a1 += w0 * bf2f(x0.y) + w1 * bf2f(x1.y) + w2 * bf2f(x2.y) + w3 * bf2f(x3.y);
        a2 += w0 * bf2f(x0.z) + w1 * bf2f(x1.z) + w2 * bf2f(x2.z) + w3 * bf2f(x3.z);
        a3 += w0 * bf2f(x0.w) + w1 * bf2f(x1.w) + w2 * bf2f(x2.w) + w3 * bf2f(x3.w);
    }
    if (dotx2) {
        ushort4 xs = *(const ushort4*)(xsub + (size_t)c * ldsub + lane * 4);
        a0 = 2.f * a0 - bf2f(xs.x);
        a1 = 2.f * a1 - bf2f(xs.y);
        a2 = 2.f * a2 - bf2f(xs.z);
        a3 = 2.f * a3 - bf2f(xs.w);
    }
    ushort4 o;
    o.x = f2bf(a0); o.y = f2bf(a1); o.z = f2bf(a2); o.w = f2bf(a3);
    *(ushort4*)(out + (size_t)c * ldo + lane * 4) = o;
}

// ---- bf16 MFMA GEMM: single-wave blocks, tile 64x64, grid (ceil(M/64), 4). ----
// No __syncthreads in K-loop (same-wave LDS ordering); register prefetch pipeline.
// ch is wave-uniform (kt>>8) -> SGPR pointer select, no scratch arrays.
// mode 0: relu -> bf16 outb (ldob), vectorized via LDS transpose.
// mode 1: +bias, relu, BN affine, fused @w2+b2 -> atomicAdd f32 logits.
__global__ __launch_bounds__(64) void k_gemm(
    const u16* __restrict__ A0, const u16* __restrict__ A1,
    const u16* __restrict__ A2, const u16* __restrict__ A3,
    int lda0, int lda1, int lda2, int lda3,
    int K, const u16* __restrict__ Bt,
    int mode,
    u16* __restrict__ outb, int ldob,
    const float* __restrict__ bias, const float* __restrict__ sc,
    const float* __restrict__ sh,
    const float* __restrict__ w2, const float* __restrict__ b2,
    float* __restrict__ outlog) {
    __shared__ __align__(16) u16 sm[2 * 64 * 40];  // As|Bs; reused as C[64][68]
    u16* As = sm;
    u16* Bs = sm + 64 * 40;
    int l = threadIdx.x;
    int m0 = blockIdx.x * 64, n0 = blockIdx.y * 64;
    int q = l >> 4, l16 = l & 15;
    int r4 = l >> 2, c4 = l & 3;  // staging: 16 rows x 4 k-chunks per round
    f32x4 acc[4][4] = {};

    uint4 avp[4], bvp[4];
    {
#pragma unroll
        for (int jr = 0; jr < 4; jr++) {
            int m = m0 + r4 + 16 * jr;
            avp[jr] = make_uint4(0u, 0u, 0u, 0u);
            if (m < NN) avp[jr] = *(const uint4*)(A0 + (size_t)m * lda0 + c4 * 8);
            bvp[jr] = *(const uint4*)(Bt + (size_t)(n0 + r4 + 16 * jr) * K + c4 * 8);
        }
    }

    for (int kt = 0; kt < K; kt += 32) {
#pragma unroll
        for (int jr = 0; jr < 4; jr++) {
            *(uint4*)&As[(r4 + 16 * jr) * 40 + c4 * 8] = avp[jr];
            *(uint4*)&Bs[(r4 + 16 * jr) * 40 + c4 * 8] = bvp[jr];
        }
        int kn = kt + 32;
        if (kn < K) {
            int ch = kn >> 8;  // wave-uniform
            const u16* ap;
            int la;
            if (ch == 0) { ap = A0; la = lda0; }
            else if (ch == 1) { ap = A1; la = lda1; }
            else if (ch == 2) { ap = A2; la = lda2; }
            else { ap = A3; la = lda3; }
            int ko = (kn & 255) + c4 * 8;
#pragma unroll
            for (int jr = 0; jr < 4; jr++) {
                int m = m0 + r4 + 16 * jr;
                avp[jr] = make_uint4(0u, 0u, 0u, 0u);
                if (m < NN) avp[jr] = *(const uint4*)(ap + (size_t)m * la + ko);
                bvp[jr] = *(const uint4*)(Bt + (size_t)(n0 + r4 + 16 * jr) * K + kn + c4 * 8);
            }
        }
        bf16x8 a[4], b[4];
#pragma unroll
        for (int mt = 0; mt < 4; mt++) a[mt] = *(const bf16x8*)&As[(mt * 16 + l16) * 40 + q * 8];
#pragma unroll
        for (int nt = 0; nt < 4; nt++) b[nt] = *(const bf16x8*)&Bs[(nt * 16 + l16) * 40 + q * 8];
#pragma unroll
        for (int nt = 0; nt < 4; nt++)
#pragma unroll
            for (int mt = 0; mt < 4; mt++)
                acc[mt][nt] =
                    __builtin_amdgcn_mfma_f32_16x16x32_bf16(a[mt], b[nt], acc[mt][nt], 0, 0, 0);
    }

    if (mode == 0) {
        __syncthreads();  // single wave: trivial; orders alias reuse of sm
        u16* Cs = sm;     // [64][68]
#pragma unroll
        for (int mt = 0; mt < 4; mt++)
#pragma unroll
            for (int nt = 0; nt < 4; nt++)
#pragma unroll
                for (int i = 0; i < 4; i++) {
                    float v = acc[mt][nt][i];
                    v = v > 0.f ? v : 0.f;
                    Cs[(mt * 16 + q * 4 + i) * 68 + nt * 16 + l16] = f2bf(v);
                }
        __syncthreads();
#pragma unroll
        for (int j = 0; j < 8; j++) {
            int r = j * 8 + (l >> 3);
            uint4 cv = *(const uint4*)&Cs[r * 68 + (l & 7) * 8];
            int row = m0 + r;
            if (row < NN) *(uint4*)(outb + (size_t)row * ldob + n0 + (l & 7) * 8) = cv;
        }
    } else {
        float bi[4], s4[4], h4[4], wa[4], wb[4];
#pragma unroll
        for (int nt = 0; nt < 4; nt++) {
            int col = n0 + nt * 16 + l16;
            bi[nt] = bias[col];
            s4[nt] = sc[col];
            h4[nt] = sh[col];
            wa[nt] = w2[2 * col];
            wb[nt] = w2[2 * col + 1];
        }
        float b20 = b2[0], b21 = b2[1];
#pragma unroll
        for (int mt = 0; mt < 4; mt++)
#pragma unroll
            for (int i = 0; i < 4; i++) {
                float p0 = 0.f, p1 = 0.f;
#pragma unroll
                for (int nt = 0; nt < 4; nt++) {
                    float v = acc[mt][nt][i] + bi[nt];
                    v = v > 0.f ? v : 0.f;
                    v = v * s4[nt] + h4[nt];
                    p0 += v * wa[nt];
                    p1 += v * wb[nt];
                }
#pragma unroll
                for (int off = 1; off < 16; off <<= 1) {
                    p0 += __shfl_xor(p0, off, 64);
                    p1 += __shfl_xor(p1, off, 64);
                }
                if (l16 == 0) {
                    int row = m0 + mt * 16 + q * 4 + i;
                    if (row < NN) {
                        float add0 = p0, add1 = p1;
                        if (blockIdx.y == 0) { add0 += b20; add1 += b21; }
                        atomicAdd(&outlog[row * 2], add0);
                        atomicAdd(&outlog[row * 2 + 1], add1);
                    }
                }
            }
    }
}

extern "C" void kernel_launch(void* const* d_in, const int* in_sizes, int n_in,
                              void* d_out, int out_size, void* d_ws, size_t ws_size,
                              hipStream_t stream) {
    const float* features = (const float*)d_in[0];
    const int* ei = (const int*)d_in[1];
    // d_in[2] = edgenet_input (bypassed by edge_weight_override)
    const float* ew = (const float*)d_in[3];
    const float* cheb_w = (const float*)d_in[4];
    const float* w1 = (const float*)d_in[5];
    const float* b1 = (const float*)d_in[6];
    const float* g = (const float*)d_in[7];
    const float* be = (const float*)d_in[8];
    const float* mn = (const float*)d_in[9];
    const float* vr = (const float*)d_in[10];
    const float* w2 = (const float*)d_in[11];
    const float* b2 = (const float*)d_in[12];
    float* out = (float*)d_out;  // [NN*2] logits, then [EE] ew

    char* p = (char*)d_ws;
    auto alloc = [&](size_t bytes) -> char* {
        char* r = p;
        p += (bytes + 255) & ~(size_t)255;
        return r;
    };
    float* deg = (float*)alloc((size_t)NN * 4);
    int* counts = (int*)alloc((size_t)(NN + 1) * 4);
    int* cursor = (int*)alloc((size_t)NN * 4);
    size_t zero_bytes = (size_t)(p - (char*)deg);
    int* offs = (int*)alloc((size_t)(NN + 1) * 4);
    int2* nbrs = (int2*)alloc((size_t)(EE + 4) * 8);
    u16* xb = (u16*)alloc((size_t)NN * 256 * 2);
    u16* tx1 = (u16*)alloc((size_t)NN * 256 * 2);
    u16* tx2 = (u16*)alloc((size_t)NN * 256 * 2);
    u16* jk = (u16*)alloc((size_t)NN * 1024 * 2);
    u16* chebT = (u16*)alloc((size_t)LGN * 3 * 256 * 256 * 2);  // per layer [256][768]
    u16* w1T = (u16*)alloc((size_t)1024 * 256 * 2);             // [256][1024]
    float* sc = (float*)alloc(256 * 4);
    float* sh = (float*)alloc(256 * 4);

    hipMemsetAsync(deg, 0, zero_bytes, stream);
    hipMemsetAsync(nbrs + EE, 0, 4 * sizeof(int2), stream);  // safe overrun pad
    hipMemsetAsync(out, 0, (size_t)NN * 2 * 4, stream);      // logits accumulated atomically
    k_edge1<<<(EE + 255) / 256, 256, 0, stream>>>(ei, ew, deg, counts, out + (size_t)NN * 2);
    k_rsqrt<<<(NN + 255) / 256, 256, 0, stream>>>(deg);
    k_scan<<<1, 1024, 0, stream>>>(counts, offs);
    k_scatter<<<(EE + 255) / 256, 256, 0, stream>>>(ei, ew, deg, offs, cursor, nbrs);
    k_cast<<<((NN * 256) + 255) / 256, 256, 0, stream>>>(features, xb, NN * 256);
    for (int i = 0; i < LGN; i++)
        k_cast_T<<<dim3(24, 8), 256, 0, stream>>>(cheb_w + (size_t)i * 768 * 256,
                                                  chebT + (size_t)i * 256 * 768, 768);
    k_cast_T<<<dim3(32, 8), 256, 0, stream>>>(w1, w1T, 1024);
    k_foldbn<<<1, 256, 0, stream>>>(g, be, mn, vr, sc, sh);

    for (int i = 0; i < LGN; i++) {
        const u16* x = (i == 0) ? xb : (jk + (size_t)(i - 1) * 256);
        int ldx = (i == 0) ? 256 : 1024;
        k_prop<<<NN / 4, 256, 0, stream>>>(x, ldx, (const u16*)nullptr, 0, 0, tx1, 256, offs,
                                           nbrs);
        k_prop<<<NN / 4, 256, 0, stream>>>(tx1, 256, x, ldx, 1, tx2, 256, offs, nbrs);
        k_gemm<<<dim3(313, 4), 64, 0, stream>>>(
            x, tx1, tx2, (const u16*)nullptr, ldx, 256, 256, 0, 768,
            chebT + (size_t)i * 256 * 768, 0, jk + (size_t)i * 256, 1024, (const float*)nullptr,
            (const float*)nullptr, (const float*)nullptr, (const float*)nullptr,
            (const float*)nullptr, (float*)nullptr);
    }
    k_gemm<<<dim3(313, 4), 64, 0, stream>>>(jk, jk + 256, jk + 512, jk + 768, 1024, 1024, 1024,
                                            1024, 1024, w1T, 1, (u16*)nullptr, 0, b1, sc, sh, w2,
                                            b2, out);
}